// Round 16
// baseline (57.424 us; speedup 1.0000x reference)
//
#include <hip/hip_runtime.h>
#include <math.h>

#define T_N 100000
#define H_N 256
#define NT16 (T_N / 16)        // 6250 16-row tiles, exact
#define NB_AT 256              // k_at grid
#define WPB 16                 // waves per block
#define NTHR (WPB * 64)        // 1024 threads
#define NWAVES (NB_AT * WPB)   // 4096 wave slots

typedef __attribute__((ext_vector_type(8))) __bf16 bf16x8;
typedef __attribute__((ext_vector_type(4))) float f32x4;

// ws layout (bytes):
//       0 : WmT bf16 [256][256]   (131072)
//  131072 : proj f32 [256]        (1024)
//  132096 : At   f32 [100000]     (400000)
//  532096 : part2 float2[256]     (2048)
//  536192 : s1g  f32[256]         (1024)
//  537216 : s0g  f32[256]         (1024)
//  538240 : lse  f32              (4)

__device__ __forceinline__ float tanh_fast(float x) {
    float e = __expf(2.0f * x);
    return 1.0f - 2.0f / (e + 1.0f);
}

// ---------------------------------------------------------------- prep
__global__ __launch_bounds__(256) void k_prep(const float* __restrict__ Wm,
                                              const float* __restrict__ hc,
                                              const float* __restrict__ W1,
                                              __bf16* __restrict__ WmT,
                                              float* __restrict__ proj,
                                              float* __restrict__ s1g,
                                              float* __restrict__ s0g) {
    const int j = blockIdx.x;
    const int t = threadIdx.x;
    WmT[j * H_N + t] = (__bf16)Wm[t * H_N + j];   // B^T, k-contiguous
    __shared__ float red[H_N];
    red[t] = hc[t] * W1[j * H_N + t];
    __syncthreads();
    for (int off = 128; off > 0; off >>= 1) {
        if (t < off) red[t] += red[t + off];
        __syncthreads();
    }
    if (t == 0) proj[j] = red[0];
    if (j == 0) { s1g[t] = 0.0f; s0g[t] = 0.0f; }
}

// ---------------------------------------------------------------- fused At + LSE + ct partials
// 1024 thr = 16 INDEPENDENT waves (no main-loop barriers), 16 waves/CU.
// tile = w*NB + bid (strided): every block gets the same 2-tile/1-tile wave
// mix -> no cross-CU idle round. Per wave-tile: af[8] (32 VGPR) from global,
// ct x-loads split around the jb loop (stay L2-hot, land under compute),
// jb over 16 col-blocks with dual MFMA chains, unroll 2.
__global__ __launch_bounds__(NTHR, 4) void k_at(const float* __restrict__ Mt,
                                                const __bf16* __restrict__ WmT,
                                                const float* __restrict__ proj,
                                                const float* __restrict__ V,
                                                float* __restrict__ At,
                                                float2* __restrict__ part2,
                                                float* __restrict__ s1g,
                                                float* __restrict__ s0g) {
    const int tid = threadIdx.x;
    const int lane = tid & 63;
    const int w = tid >> 6;     // 0..15
    const int l15 = lane & 15;
    const int lg = lane >> 4;   // 0..3

    struct SMem {
        __align__(16) char sB[131072];   // [n=256][k=256] bf16, XOR-swizzled
        float pj[256];
        float vj[256];
        float lsem[WPB], lses[WPB];
    };
    __shared__ SMem sm;

    // ---- B prologue (WmT L2-hot after k_prep)
    for (int g = tid; g < 8192; g += NTHR) {
        const int n = g >> 5;
        const int c = g & 31;
        const bf16x8 v = *(const bf16x8*)(WmT + n * H_N + c * 8);
        *(bf16x8*)(&sm.sB[(n * 512 + c * 16) ^ ((n & 7) << 4)]) = v;
    }
    if (tid < 256) { sm.pj[tid] = proj[tid]; sm.vj[tid] = V[tid]; }
    __syncthreads();   // ONLY barrier before the epilogue

    float lm = -1e30f, ls = 0.0f;
    float s1a[4] = {0.f, 0.f, 0.f, 0.f};
    float s0a[4] = {0.f, 0.f, 0.f, 0.f};

    for (int tile = w * NB_AT + blockIdx.x; tile < NT16; tile += NWAVES) {
        const float* arow = Mt + (size_t)(tile * 16 + l15) * H_N;
        const float* crow = Mt + (size_t)tile * 16 * H_N + lane * 4;

        // ---- A fragments (cvt at load; 32 VGPR)
        bf16x8 af[8];
#pragma unroll
        for (int ks = 0; ks < 8; ++ks) {
            const float4 a0 = *(const float4*)(arow + 32 * ks + 8 * lg);
            const float4 a1 = *(const float4*)(arow + 32 * ks + 8 * lg + 4);
            af[ks][0] = (__bf16)a0.x; af[ks][1] = (__bf16)a0.y;
            af[ks][2] = (__bf16)a0.z; af[ks][3] = (__bf16)a0.w;
            af[ks][4] = (__bf16)a1.x; af[ks][5] = (__bf16)a1.y;
            af[ks][6] = (__bf16)a1.z; af[ks][7] = (__bf16)a1.w;
        }

        // ---- hoisted ct loads, first half (land under jb compute)
        float4 x0[8];
#pragma unroll
        for (int r = 0; r < 8; ++r)
            x0[r] = *(const float4*)(crow + (size_t)r * H_N);

        // ---- jb loop: 16 col-blocks, dual chains, 2 blocks in flight
        float pacc[4] = {0.f, 0.f, 0.f, 0.f};
#pragma unroll 2
        for (int jb = 0; jb < 16; ++jb) {
            f32x4 accA = {0.f, 0.f, 0.f, 0.f};
            f32x4 accB = {0.f, 0.f, 0.f, 0.f};
            const int n = 16 * jb + l15;
            const int nb = n * 512;
            const int nswz = (n & 7) << 4;
#pragma unroll
            for (int ks = 0; ks < 4; ++ks) {
                const bf16x8 bfA = *(const bf16x8*)(
                    &sm.sB[nb + (((32 * ks + 8 * lg) * 2) ^ nswz)]);
                const bf16x8 bfB = *(const bf16x8*)(
                    &sm.sB[nb + (((32 * (ks + 4) + 8 * lg) * 2) ^ nswz)]);
                accA = __builtin_amdgcn_mfma_f32_16x16x32_bf16(af[ks], bfA, accA, 0, 0, 0);
                accB = __builtin_amdgcn_mfma_f32_16x16x32_bf16(af[ks + 4], bfB, accB, 0, 0, 0);
            }
            const float pjv = sm.pj[n], vjv = sm.vj[n];
#pragma unroll
            for (int i = 0; i < 4; ++i)
                pacc[i] += tanh_fast(accA[i] + accB[i] + pjv) * vjv;
        }

        // ---- row sums: butterfly over the 16 lanes of each lg group
        float p[4];
#pragma unroll
        for (int i = 0; i < 4; ++i) {
            float q = pacc[i];
            q += __shfl_xor(q, 1);
            q += __shfl_xor(q, 2);
            q += __shfl_xor(q, 4);
            q += __shfl_xor(q, 8);
            p[i] = q;
        }
        if (l15 == 0) {
#pragma unroll
            for (int i = 0; i < 4; ++i) {
                const float at = p[i];
                At[tile * 16 + 4 * lg + i] = at;
                if (at > lm) { ls = ls * __expf(lm - at) + 1.0f; lm = at; }
                else ls += __expf(at - lm);
            }
        }

        // ---- second half of ct loads (issued before the FMA pass)
        float4 x1[8];
#pragma unroll
        for (int r = 0; r < 8; ++r)
            x1[r] = *(const float4*)(crow + (size_t)(8 + r) * H_N);

        // ---- ct partials
#pragma unroll
        for (int r = 0; r < 8; ++r) {
            const float atr = __shfl(p[r & 3], 16 * (r >> 2));
            s1a[0] += atr * x0[r].x; s1a[1] += atr * x0[r].y;
            s1a[2] += atr * x0[r].z; s1a[3] += atr * x0[r].w;
            s0a[0] += x0[r].x; s0a[1] += x0[r].y;
            s0a[2] += x0[r].z; s0a[3] += x0[r].w;
        }
#pragma unroll
        for (int r = 8; r < 16; ++r) {
            const float atr = __shfl(p[r & 3], 16 * (r >> 2));
            s1a[0] += atr * x1[r - 8].x; s1a[1] += atr * x1[r - 8].y;
            s1a[2] += atr * x1[r - 8].z; s1a[3] += atr * x1[r - 8].w;
            s0a[0] += x1[r - 8].x; s0a[1] += x1[r - 8].y;
            s0a[2] += x1[r - 8].z; s0a[3] += x1[r - 8].w;
        }
    }

    // ---- wave LSE partial -> shared
#pragma unroll
    for (int d = 1; d < 64; d <<= 1) {
        const float m2 = __shfl_xor(lm, d), s2 = __shfl_xor(ls, d);
        const float M = fmaxf(lm, m2);
        ls = ls * __expf(lm - M) + s2 * __expf(m2 - M);
        lm = M;
    }
    if (lane == 0) { sm.lsem[w] = lm; sm.lses[w] = ls; }

    // ---- block reduce of ct partials (reuse sB region)
    __syncthreads();
    float* red1 = (float*)&sm.sB[0];       // [16][256]
    float* red2 = (float*)&sm.sB[65536];   // [16][256]
#pragma unroll
    for (int q = 0; q < 4; ++q) {
        red1[w * 256 + lane * 4 + q] = s1a[q];
        red2[w * 256 + lane * 4 + q] = s0a[q];
    }
    __syncthreads();
    if (tid < 256) {
        float a = 0.f;
#pragma unroll
        for (int g = 0; g < WPB; ++g) a += red1[g * 256 + tid];
        atomicAdd(&s1g[tid], a);
    } else if (tid < 512) {
        const int c = tid - 256;
        float a = 0.f;
#pragma unroll
        for (int g = 0; g < WPB; ++g) a += red2[g * 256 + c];
        atomicAdd(&s0g[c], a);
    } else if (tid == 512) {
        float m = sm.lsem[0], s = sm.lses[0];
#pragma unroll
        for (int g = 1; g < WPB; ++g) {
            const float m2 = sm.lsem[g], s2 = sm.lses[g];
            const float M = fmaxf(m, m2);
            s = s * __expf(m - M) + s2 * __expf(m2 - M);
            m = M;
        }
        part2[blockIdx.x] = make_float2(m, s);
    }
}

// ---------------------------------------------------------------- final: LSE + ct
__global__ __launch_bounds__(256) void k_final(const float2* __restrict__ part2,
                                               const float* __restrict__ s1g,
                                               const float* __restrict__ s0g,
                                               float* __restrict__ lse,
                                               float* __restrict__ out) {
    const int tid = threadIdx.x;
    __shared__ float ms[256], ss[256];
    const float2 p = part2[tid];
    ms[tid] = p.x; ss[tid] = p.y;
    __syncthreads();
    for (int off = 128; off > 0; off >>= 1) {
        if (tid < off) {
            const float m2 = ms[tid + off], s2 = ss[tid + off];
            const float M = fmaxf(ms[tid], m2);
            ss[tid] = ss[tid] * __expf(ms[tid] - M) + s2 * __expf(m2 - M);
            ms[tid] = M;
        }
        __syncthreads();
    }
    __shared__ float Ls;
    if (tid == 0) { Ls = ms[0] + logf(ss[0]); *lse = Ls; }
    __syncthreads();
    out[T_N + tid] = s1g[tid] - Ls * s0g[tid];
}

// ---------------------------------------------------------------- alphat = At - LSE
__global__ __launch_bounds__(256) void k_alpha(const float* __restrict__ At,
                                               const float* __restrict__ lse,
                                               float* __restrict__ out) {
    const float L = *lse;
    const int i4 = blockIdx.x * 256 + threadIdx.x;
    if (i4 < T_N / 4) {
        float4 a = *(const float4*)(At + i4 * 4);
        a.x -= L; a.y -= L; a.z -= L; a.w -= L;
        *(float4*)(out + i4 * 4) = a;
    }
}

// ----------------------------------------------------------------
extern "C" void kernel_launch(void* const* d_in, const int* in_sizes, int n_in,
                              void* d_out, int out_size, void* d_ws, size_t ws_size,
                              hipStream_t stream) {
    const float* inputs = (const float*)d_in[0];  // (T, H)
    const float* hc     = (const float*)d_in[1];  // (1, H)
    const float* Wm     = (const float*)d_in[2];  // (H, H)
    const float* V      = (const float*)d_in[3];  // (H, 1)
    const float* W1     = (const float*)d_in[4];  // (H, H)
    float* out = (float*)d_out;                   // [alphat (T) | ct (H)]

    char* ws = (char*)d_ws;
    __bf16* WmT  = (__bf16*)ws;
    float* proj  = (float*)(ws + 131072);
    float* At    = (float*)(ws + 132096);
    float2* p2   = (float2*)(ws + 532096);
    float* s1g   = (float*)(ws + 536192);
    float* s0g   = (float*)(ws + 537216);
    float* lse   = (float*)(ws + 538240);

    k_prep<<<256, 256, 0, stream>>>(Wm, hc, W1, WmT, proj, s1g, s0g);
    k_at<<<NB_AT, NTHR, 0, stream>>>(inputs, WmT, proj, V, At, p2, s1g, s0g);
    k_final<<<1, 256, 0, stream>>>(p2, s1g, s0g, lse, out);
    k_alpha<<<98, 256, 0, stream>>>(At, lse, out);
}